// Round 1
// baseline (3201.243 us; speedup 1.0000x reference)
//
#include <hip/hip_runtime.h>

// ---------------------------------------------------------------------------
// DirSageConv: out = x@W_self + b_self
//                  + 0.5*(mean_{in}(x) @ W_s2d + b_s2d)
//                  + 0.5*(mean_{out}(x) @ W_d2s + b_d2s)
// N=100000, E=800000, D=128, f32 everywhere.
//
// Schedule (all on `stream`):
//   1. memset ws: sum[N*128], cnt_in[N], cnt_out[N] = 0
//   2. count_k:   cnt_in[dst]++, cnt_out[src]++        (edge atomics)
//   3. scale_k:   sc = 0.5/max(cnt,1)
//   4. scatter_k dir0: sum[dst] += x[src]              (agg_in * cnt)
//   5. gemm_k pass1: out = x@W_self + (sum*sc_in)@W_s2d + bias
//   6. memset sum = 0
//   7. scatter_k dir1: sum[src] += x[dst]              (agg_out * cnt)
//   8. gemm_k pass2: out += (sum*sc_out)@W_d2s
// ---------------------------------------------------------------------------

#define D 128

__global__ __launch_bounds__(256) void count_k(const int* __restrict__ ei, int E,
                                               float* __restrict__ cnt_in,
                                               float* __restrict__ cnt_out) {
    int e = blockIdx.x * 256 + threadIdx.x;
    if (e >= E) return;
    int src = ei[e];
    int dst = ei[E + e];
    atomicAdd(&cnt_in[dst], 1.0f);
    atomicAdd(&cnt_out[src], 1.0f);
}

__global__ __launch_bounds__(256) void scale_k(const float* __restrict__ cnt_in,
                                               const float* __restrict__ cnt_out,
                                               float* __restrict__ sc_in,
                                               float* __restrict__ sc_out, int N) {
    int n = blockIdx.x * 256 + threadIdx.x;
    if (n >= N) return;
    sc_in[n]  = 0.5f / fmaxf(cnt_in[n], 1.0f);
    sc_out[n] = 0.5f / fmaxf(cnt_out[n], 1.0f);
}

// dir==0: sum[dst] += x[src]   (in-aggregation)
// dir==1: sum[src] += x[dst]   (out-aggregation)
__global__ __launch_bounds__(256) void scatter_k(const float* __restrict__ x,
                                                 const int* __restrict__ ei, int E,
                                                 float* __restrict__ sum, int dir) {
    int gid = blockIdx.x * 256 + threadIdx.x;
    int e = gid >> 5;       // 32 chunks of float4 per 128-wide row
    int c = gid & 31;
    if (e >= E) return;
    int u = ei[e];          // src
    int v = ei[E + e];      // dst
    int from = dir ? v : u;
    int to   = dir ? u : v;
    const float4 val = *(const float4*)&x[(long long)from * D + c * 4];
    float* p = &sum[(long long)to * D + c * 4];
    atomicAdd(p + 0, val.x);
    atomicAdd(p + 1, val.y);
    atomicAdd(p + 2, val.z);
    atomicAdd(p + 3, val.w);
}

// C[64 x 128] tile per block. 256 threads: thread -> 8 rows x 4 cols (32 acc).
// Up to two segments: acc += (A_s * sc_s(row)) @ W_s.  sc==nullptr -> 1.0.
// b0 != nullptr -> add b0 + 0.5*(b1+b2).  accum -> out += instead of out =.
__global__ __launch_bounds__(256) void gemm_k(
    const float* __restrict__ A0, const float* __restrict__ sc0, const float* __restrict__ W0,
    const float* __restrict__ A1, const float* __restrict__ sc1, const float* __restrict__ W1,
    const float* __restrict__ b0, const float* __restrict__ b1, const float* __restrict__ b2,
    float* __restrict__ out, int N, int accum) {
    __shared__ float Xs[64][36];   // 32-k chunk, +4 pad keeps float4 align, breaks stride
    __shared__ float Ws[32][128];  // 32-k chunk of weights

    const int tid = threadIdx.x;
    const int c4 = tid & 31;   // columns c4*4 .. c4*4+3
    const int rg = tid >> 5;   // rows rg*8 .. rg*8+7
    const int row0 = blockIdx.x * 64;

    float acc[8][4];
#pragma unroll
    for (int j = 0; j < 8; ++j)
#pragma unroll
        for (int m = 0; m < 4; ++m) acc[j][m] = 0.0f;

    for (int seg = 0; seg < 2; ++seg) {
        const float* A  = seg ? A1 : A0;
        if (!A) break;
        const float* sc = seg ? sc1 : sc0;
        const float* W  = seg ? W1 : W0;

        for (int kb = 0; kb < 4; ++kb) {
            __syncthreads();  // protect LDS from previous chunk's readers
            // stage A tile: 64 rows x 32 k = 512 float4
#pragma unroll
            for (int i = 0; i < 2; ++i) {
                int f4 = tid + i * 256;
                int r = f4 >> 3;
                int kk4 = f4 & 7;
                int grow = row0 + r;
                float4 v = make_float4(0.f, 0.f, 0.f, 0.f);
                if (grow < N) {
                    v = *(const float4*)&A[(long long)grow * D + kb * 32 + kk4 * 4];
                    if (sc) {
                        float s = sc[grow];
                        v.x *= s; v.y *= s; v.z *= s; v.w *= s;
                    }
                }
                *(float4*)&Xs[r][kk4 * 4] = v;
            }
            // stage W chunk: 32 k x 128 cols = 1024 float4
#pragma unroll
            for (int i = 0; i < 4; ++i) {
                int f4 = tid + i * 256;
                int kk = f4 >> 5;
                int cc = f4 & 31;
                *(float4*)&Ws[kk][cc * 4] = *(const float4*)&W[(kb * 32 + kk) * D + cc * 4];
            }
            __syncthreads();

#pragma unroll
            for (int kk = 0; kk < 32; kk += 4) {
                float4 w[4];
#pragma unroll
                for (int m = 0; m < 4; ++m) w[m] = *(float4*)&Ws[kk + m][c4 * 4];
#pragma unroll
                for (int j = 0; j < 8; ++j) {
                    float4 a = *(float4*)&Xs[rg * 8 + j][kk];
                    acc[j][0] += a.x * w[0].x + a.y * w[1].x + a.z * w[2].x + a.w * w[3].x;
                    acc[j][1] += a.x * w[0].y + a.y * w[1].y + a.z * w[2].y + a.w * w[3].y;
                    acc[j][2] += a.x * w[0].z + a.y * w[1].z + a.z * w[2].z + a.w * w[3].z;
                    acc[j][3] += a.x * w[0].w + a.y * w[1].w + a.z * w[2].w + a.w * w[3].w;
                }
            }
        }
    }

    float4 bias = make_float4(0.f, 0.f, 0.f, 0.f);
    if (b0) {
        int c = c4 * 4;
        bias.x = b0[c + 0] + 0.5f * (b1[c + 0] + b2[c + 0]);
        bias.y = b0[c + 1] + 0.5f * (b1[c + 1] + b2[c + 1]);
        bias.z = b0[c + 2] + 0.5f * (b1[c + 2] + b2[c + 2]);
        bias.w = b0[c + 3] + 0.5f * (b1[c + 3] + b2[c + 3]);
    }
#pragma unroll
    for (int j = 0; j < 8; ++j) {
        int row = row0 + rg * 8 + j;
        if (row >= N) continue;
        float4 o;
        o.x = acc[j][0] + bias.x;
        o.y = acc[j][1] + bias.y;
        o.z = acc[j][2] + bias.z;
        o.w = acc[j][3] + bias.w;
        float* op = &out[(long long)row * D + c4 * 4];
        if (accum) {
            float4 prev = *(float4*)op;
            o.x += prev.x; o.y += prev.y; o.z += prev.z; o.w += prev.w;
        }
        *(float4*)op = o;
    }
}

extern "C" void kernel_launch(void* const* d_in, const int* in_sizes, int n_in,
                              void* d_out, int out_size, void* d_ws, size_t ws_size,
                              hipStream_t stream) {
    const float* x      = (const float*)d_in[0];
    const float* W_self = (const float*)d_in[1];
    const float* b_self = (const float*)d_in[2];
    const float* W_s2d  = (const float*)d_in[3];
    const float* b_s2d  = (const float*)d_in[4];
    const float* W_d2s  = (const float*)d_in[5];
    const float* b_d2s  = (const float*)d_in[6];
    const int*   ei     = (const int*)d_in[7];

    const int N = in_sizes[0] / D;
    const int E = in_sizes[7] / 2;

    float* sum     = (float*)d_ws;               // N*128
    float* cnt_in  = sum + (size_t)N * D;        // N
    float* cnt_out = cnt_in + N;                 // N
    float* sc_in   = cnt_out + N;                // N
    float* sc_out  = sc_in + N;                  // N

    float* out = (float*)d_out;

    const int edge_blocks    = (E + 255) / 256;
    const int node_blocks    = (N + 255) / 256;
    const int scatter_blocks = (E * 32 + 255) / 256;
    const int gemm_blocks    = (N + 63) / 64;

    // 1. zero sum + counts
    hipMemsetAsync(d_ws, 0, ((size_t)N * D + 2 * (size_t)N) * sizeof(float), stream);
    // 2-3. degree counts and scales
    count_k<<<edge_blocks, 256, 0, stream>>>(ei, E, cnt_in, cnt_out);
    scale_k<<<node_blocks, 256, 0, stream>>>(cnt_in, cnt_out, sc_in, sc_out, N);
    // 4. in-aggregation: sum[dst] += x[src]
    scatter_k<<<scatter_blocks, 256, 0, stream>>>(x, ei, E, sum, 0);
    // 5. out = x@W_self + (sum*sc_in)@W_s2d + bias
    gemm_k<<<gemm_blocks, 256, 0, stream>>>(x, nullptr, W_self,
                                            sum, sc_in, W_s2d,
                                            b_self, b_s2d, b_d2s,
                                            out, N, 0);
    // 6. re-zero sum for second direction
    hipMemsetAsync(sum, 0, (size_t)N * D * sizeof(float), stream);
    // 7. out-aggregation: sum[src] += x[dst]
    scatter_k<<<scatter_blocks, 256, 0, stream>>>(x, ei, E, sum, 1);
    // 8. out += (sum*sc_out)@W_d2s
    gemm_k<<<gemm_blocks, 256, 0, stream>>>(sum, sc_out, W_d2s,
                                            nullptr, nullptr, nullptr,
                                            nullptr, nullptr, nullptr,
                                            out, N, 1);
}

// Round 2
// 690.183 us; speedup vs baseline: 4.6383x; 4.6383x over previous
//
#include <hip/hip_runtime.h>

// ---------------------------------------------------------------------------
// DirSageConv via device-built CSR + gather-mean (no feature atomics)
//   out = x@W_self + b_self + 0.5*(mean_in(x)@W_s2d + b_s2d)
//                           + 0.5*(mean_out(x)@W_d2s + b_d2s)
// N=100000, E=800000, D=128, f32.
//
// plan2 (ws >= ~111MB): CSR both dirs, agg both, ONE fused 3-segment GEMM.
// plan1 (ws >= ~56MB):  CSR per dir sequentially, 2-seg GEMM + 1-seg accum.
// plan0: round-1 atomic scatter fallback.
// ---------------------------------------------------------------------------

#define D 128

// ---------------- degree / CSR build ----------------

__global__ __launch_bounds__(256) void deg_k(const int* __restrict__ ei, int E,
                                             int* __restrict__ deg_in,
                                             int* __restrict__ deg_out) {
    int e = blockIdx.x * 256 + threadIdx.x;
    if (e >= E) return;
    atomicAdd(&deg_out[ei[e]], 1);      // src out-degree
    atomicAdd(&deg_in[ei[E + e]], 1);   // dst in-degree
}

__device__ __forceinline__ int block_incl_scan(int v, int* wsum) {
    int lane = threadIdx.x & 63;
    int wv = threadIdx.x >> 6;
#pragma unroll
    for (int off = 1; off < 64; off <<= 1) {
        int t = __shfl_up(v, off, 64);
        if (lane >= off) v += t;
    }
    if (lane == 63) wsum[wv] = v;
    __syncthreads();
    int add = 0;
    for (int w = 0; w < wv; ++w) add += wsum[w];
    return v + add;
}

__global__ __launch_bounds__(256) void scan1_k(const int* __restrict__ in, int n,
                                               int* __restrict__ bsum) {
    __shared__ int wsum[4];
    int i = blockIdx.x * 256 + threadIdx.x;
    int v = (i < n) ? in[i] : 0;
    int s = block_incl_scan(v, wsum);
    if (threadIdx.x == 255) bsum[blockIdx.x] = s;
}

__global__ __launch_bounds__(1024) void scan2_k(int* __restrict__ bsum, int nb) {
    __shared__ int wsum[16];
    int i = threadIdx.x;
    int v = (i < nb) ? bsum[i] : 0;
    int s = block_incl_scan(v, wsum);
    if (i < nb) bsum[i] = s - v;   // exclusive
}

__global__ __launch_bounds__(256) void scan3_k(const int* __restrict__ in, int n,
                                               const int* __restrict__ bsum,
                                               int* __restrict__ ptr) {
    __shared__ int wsum[4];
    int i = blockIdx.x * 256 + threadIdx.x;
    int v = (i < n) ? in[i] : 0;
    int s = block_incl_scan(v, wsum);
    int off = bsum[blockIdx.x];
    if (i < n) ptr[i] = off + s - v;   // exclusive scan
    if (i == n - 1) ptr[n] = off + s;  // total = E
}

__global__ __launch_bounds__(256) void fill2_k(const int* __restrict__ ei, int E,
                                               int* __restrict__ cur_in,
                                               int* __restrict__ cur_out,
                                               int* __restrict__ adj_in,
                                               int* __restrict__ adj_out) {
    int e = blockIdx.x * 256 + threadIdx.x;
    if (e >= E) return;
    int s = ei[e], d = ei[E + e];
    adj_in[atomicAdd(&cur_in[d], 1)] = s;   // in-neighbors of d
    adj_out[atomicAdd(&cur_out[s], 1)] = d; // out-neighbors of s
}

// dir==0: neighbors-at-dst gathering src. dir==1: neighbors-at-src gathering dst.
__global__ __launch_bounds__(256) void fill1_k(const int* __restrict__ ei, int E, int dir,
                                               int* __restrict__ cur, int* __restrict__ adj) {
    int e = blockIdx.x * 256 + threadIdx.x;
    if (e >= E) return;
    int s = ei[e], d = ei[E + e];
    int to = dir ? s : d;
    int fr = dir ? d : s;
    adj[atomicAdd(&cur[to], 1)] = fr;
}

// ---------------- gather-mean aggregation ----------------
// 32 threads per node; thread c owns float4 columns c*4..c*4+3.
// Writes sum[node] = 0.5/max(deg,1) * sum_{nbr} x[nbr]  (every node written).
__global__ __launch_bounds__(256) void agg_k(const float* __restrict__ x,
                                             const int* __restrict__ ptr,
                                             const int* __restrict__ adj,
                                             float* __restrict__ outsum, int N) {
    int gid = blockIdx.x * 256 + threadIdx.x;
    int node = gid >> 5;
    int c = gid & 31;
    if (node >= N) return;
    int beg = ptr[node], end = ptr[node + 1];
    float4 acc = make_float4(0.f, 0.f, 0.f, 0.f);
    for (int j0 = beg; j0 < end; j0 += 32) {
        int a = (j0 + c < end) ? adj[j0 + c] : 0;  // coalesced batch of indices
        int m = min(32, end - j0);
        for (int t = 0; t < m; ++t) {
            int nbr = __shfl(a, t, 32);
            const float4 v = *(const float4*)&x[(size_t)nbr * D + c * 4];
            acc.x += v.x; acc.y += v.y; acc.z += v.z; acc.w += v.w;
        }
    }
    float s = 0.5f / fmaxf((float)(end - beg), 1.0f);
    float4 o = make_float4(acc.x * s, acc.y * s, acc.z * s, acc.w * s);
    *(float4*)&outsum[(size_t)node * D + c * 4] = o;
}

// ---------------- plan0 fallback: atomic scatter ----------------

__global__ __launch_bounds__(256) void scatter_k(const float* __restrict__ x,
                                                 const int* __restrict__ ei, int E,
                                                 float* __restrict__ sum, int dir) {
    int gid = blockIdx.x * 256 + threadIdx.x;
    int e = gid >> 5;
    int c = gid & 31;
    if (e >= E) return;
    int u = ei[e];
    int v = ei[E + e];
    int from = dir ? v : u;
    int to   = dir ? u : v;
    const float4 val = *(const float4*)&x[(size_t)from * D + c * 4];
    float* p = &sum[(size_t)to * D + c * 4];
    atomicAdd(p + 0, val.x);
    atomicAdd(p + 1, val.y);
    atomicAdd(p + 2, val.z);
    atomicAdd(p + 3, val.w);
}

__global__ __launch_bounds__(256) void norm_k(float* __restrict__ sum,
                                              const int* __restrict__ deg, int N) {
    int gid = blockIdx.x * 256 + threadIdx.x;
    int node = gid >> 5;
    int c = gid & 31;
    if (node >= N) return;
    float s = 0.5f / fmaxf((float)deg[node], 1.0f);
    float4* p = (float4*)&sum[(size_t)node * D + c * 4];
    float4 v = *p;
    v.x *= s; v.y *= s; v.z *= s; v.w *= s;
    *p = v;
}

// ---------------- fused multi-segment GEMM ----------------
// C[64 x 128] tile per block, 256 threads: 8 rows x 4 cols per thread.
// acc = sum over non-null segments of A_s @ W_s.  Bias: b0 + 0.5*(b1+b2) if b0.
// accum -> out += instead of out =.
__global__ __launch_bounds__(256) void gemm_k(
    const float* __restrict__ A0, const float* __restrict__ W0,
    const float* __restrict__ A1, const float* __restrict__ W1,
    const float* __restrict__ A2, const float* __restrict__ W2,
    const float* __restrict__ b0, const float* __restrict__ b1, const float* __restrict__ b2,
    float* __restrict__ out, int N, int accum) {
    __shared__ float Xs[64][36];
    __shared__ float Ws[32][128];

    const int tid = threadIdx.x;
    const int c4 = tid & 31;
    const int rg = tid >> 5;
    const int row0 = blockIdx.x * 64;

    float acc[8][4];
#pragma unroll
    for (int j = 0; j < 8; ++j)
#pragma unroll
        for (int m = 0; m < 4; ++m) acc[j][m] = 0.0f;

    for (int seg = 0; seg < 3; ++seg) {
        const float* A = (seg == 0) ? A0 : (seg == 1) ? A1 : A2;
        if (!A) continue;
        const float* W = (seg == 0) ? W0 : (seg == 1) ? W1 : W2;

        for (int kb = 0; kb < 4; ++kb) {
            __syncthreads();
#pragma unroll
            for (int i = 0; i < 2; ++i) {
                int f4 = tid + i * 256;
                int r = f4 >> 3;
                int kk4 = f4 & 7;
                int grow = row0 + r;
                float4 v = make_float4(0.f, 0.f, 0.f, 0.f);
                if (grow < N)
                    v = *(const float4*)&A[(size_t)grow * D + kb * 32 + kk4 * 4];
                *(float4*)&Xs[r][kk4 * 4] = v;
            }
#pragma unroll
            for (int i = 0; i < 4; ++i) {
                int f4 = tid + i * 256;
                int kk = f4 >> 5;
                int cc = f4 & 31;
                *(float4*)&Ws[kk][cc * 4] = *(const float4*)&W[(kb * 32 + kk) * D + cc * 4];
            }
            __syncthreads();

#pragma unroll
            for (int kk = 0; kk < 32; kk += 4) {
                float4 w[4];
#pragma unroll
                for (int m = 0; m < 4; ++m) w[m] = *(float4*)&Ws[kk + m][c4 * 4];
#pragma unroll
                for (int j = 0; j < 8; ++j) {
                    float4 a = *(float4*)&Xs[rg * 8 + j][kk];
                    acc[j][0] += a.x * w[0].x + a.y * w[1].x + a.z * w[2].x + a.w * w[3].x;
                    acc[j][1] += a.x * w[0].y + a.y * w[1].y + a.z * w[2].y + a.w * w[3].y;
                    acc[j][2] += a.x * w[0].z + a.y * w[1].z + a.z * w[2].z + a.w * w[3].z;
                    acc[j][3] += a.x * w[0].w + a.y * w[1].w + a.z * w[2].w + a.w * w[3].w;
                }
            }
        }
    }

    float4 bias = make_float4(0.f, 0.f, 0.f, 0.f);
    if (b0) {
        int c = c4 * 4;
        bias.x = b0[c + 0] + 0.5f * (b1[c + 0] + b2[c + 0]);
        bias.y = b0[c + 1] + 0.5f * (b1[c + 1] + b2[c + 1]);
        bias.z = b0[c + 2] + 0.5f * (b1[c + 2] + b2[c + 2]);
        bias.w = b0[c + 3] + 0.5f * (b1[c + 3] + b2[c + 3]);
    }
#pragma unroll
    for (int j = 0; j < 8; ++j) {
        int row = row0 + rg * 8 + j;
        if (row >= N) continue;
        float4 o;
        o.x = acc[j][0] + bias.x;
        o.y = acc[j][1] + bias.y;
        o.z = acc[j][2] + bias.z;
        o.w = acc[j][3] + bias.w;
        float* op = &out[(size_t)row * D + c4 * 4];
        if (accum) {
            float4 prev = *(float4*)op;
            o.x += prev.x; o.y += prev.y; o.z += prev.z; o.w += prev.w;
        }
        *(float4*)op = o;
    }
}

// ---------------------------------------------------------------------------

extern "C" void kernel_launch(void* const* d_in, const int* in_sizes, int n_in,
                              void* d_out, int out_size, void* d_ws, size_t ws_size,
                              hipStream_t stream) {
    const float* x      = (const float*)d_in[0];
    const float* W_self = (const float*)d_in[1];
    const float* b_self = (const float*)d_in[2];
    const float* W_s2d  = (const float*)d_in[3];
    const float* b_s2d  = (const float*)d_in[4];
    const float* W_d2s  = (const float*)d_in[5];
    const float* b_d2s  = (const float*)d_in[6];
    const int*   ei     = (const int*)d_in[7];

    const int N = in_sizes[0] / D;
    const int E = in_sizes[7] / 2;
    float* out = (float*)d_out;
    char* ws = (char*)d_ws;

    const size_t fbytes = (size_t)N * D * sizeof(float);
    const size_t nInt = (size_t)N * sizeof(int);
    const size_t pInt = (size_t)(N + 1) * sizeof(int);
    const size_t eInt = (size_t)E * sizeof(int);
    const int nb = (N + 255) / 256;                 // 391 <= 1024

    const int edge_blocks = (E + 255) / 256;
    const int node32_blocks = (int)(((size_t)N * 32 + 255) / 256);
    const int gemm_blocks = (N + 63) / 64;

    // ---- plan2 layout ----
    size_t o2 = 0;
    size_t o_sum_in = o2;  o2 += fbytes;
    size_t o_sum_out = o2; o2 += fbytes;
    size_t o_deg_in = o2;  o2 += nInt;
    size_t o_deg_out = o2; o2 += nInt;
    size_t o_ptr_in = o2;  o2 += pInt;
    size_t o_ptr_out = o2; o2 += pInt;
    size_t o_cur_in = o2;  o2 += nInt;
    size_t o_cur_out = o2; o2 += nInt;
    size_t o_adj_in = o2;  o2 += eInt;
    size_t o_adj_out = o2; o2 += eInt;
    size_t o_bs2 = o2;     o2 += 1024 * sizeof(int);
    const size_t need2 = o2;

    // ---- plan1 layout ----
    size_t o1 = 0;
    size_t p_sum = o1;  o1 += fbytes;
    size_t p_deg_in = o1;  o1 += nInt;
    size_t p_deg_out = o1; o1 += nInt;
    size_t p_ptr = o1;  o1 += pInt;
    size_t p_cur = o1;  o1 += nInt;
    size_t p_adj = o1;  o1 += eInt;
    size_t p_bs = o1;   o1 += 1024 * sizeof(int);
    const size_t need1 = o1;

    const int plan = (ws_size >= need2) ? 2 : (ws_size >= need1) ? 1 : 0;

    if (plan == 2) {
        int* deg_in  = (int*)(ws + o_deg_in);
        int* deg_out = (int*)(ws + o_deg_out);
        int* ptr_in  = (int*)(ws + o_ptr_in);
        int* ptr_out = (int*)(ws + o_ptr_out);
        int* cur_in  = (int*)(ws + o_cur_in);
        int* cur_out = (int*)(ws + o_cur_out);
        int* adj_in  = (int*)(ws + o_adj_in);
        int* adj_out = (int*)(ws + o_adj_out);
        int* bs      = (int*)(ws + o_bs2);
        float* sum_in  = (float*)(ws + o_sum_in);
        float* sum_out = (float*)(ws + o_sum_out);

        hipMemsetAsync(deg_in, 0, 2 * nInt, stream);  // deg_in+deg_out contiguous
        deg_k<<<edge_blocks, 256, 0, stream>>>(ei, E, deg_in, deg_out);

        scan1_k<<<nb, 256, 0, stream>>>(deg_in, N, bs);
        scan2_k<<<1, 1024, 0, stream>>>(bs, nb);
        scan3_k<<<nb, 256, 0, stream>>>(deg_in, N, bs, ptr_in);
        scan1_k<<<nb, 256, 0, stream>>>(deg_out, N, bs);
        scan2_k<<<1, 1024, 0, stream>>>(bs, nb);
        scan3_k<<<nb, 256, 0, stream>>>(deg_out, N, bs, ptr_out);

        hipMemcpyAsync(cur_in, ptr_in, nInt, hipMemcpyDeviceToDevice, stream);
        hipMemcpyAsync(cur_out, ptr_out, nInt, hipMemcpyDeviceToDevice, stream);
        fill2_k<<<edge_blocks, 256, 0, stream>>>(ei, E, cur_in, cur_out, adj_in, adj_out);

        agg_k<<<node32_blocks, 256, 0, stream>>>(x, ptr_in, adj_in, sum_in, N);
        agg_k<<<node32_blocks, 256, 0, stream>>>(x, ptr_out, adj_out, sum_out, N);

        gemm_k<<<gemm_blocks, 256, 0, stream>>>(x, W_self, sum_in, W_s2d, sum_out, W_d2s,
                                                b_self, b_s2d, b_d2s, out, N, 0);
    } else if (plan == 1) {
        int* deg_in  = (int*)(ws + p_deg_in);
        int* deg_out = (int*)(ws + p_deg_out);
        int* ptr = (int*)(ws + p_ptr);
        int* cur = (int*)(ws + p_cur);
        int* adj = (int*)(ws + p_adj);
        int* bs  = (int*)(ws + p_bs);
        float* sum = (float*)(ws + p_sum);

        hipMemsetAsync(deg_in, 0, 2 * nInt, stream);
        deg_k<<<edge_blocks, 256, 0, stream>>>(ei, E, deg_in, deg_out);

        // dir 0: in-aggregation
        scan1_k<<<nb, 256, 0, stream>>>(deg_in, N, bs);
        scan2_k<<<1, 1024, 0, stream>>>(bs, nb);
        scan3_k<<<nb, 256, 0, stream>>>(deg_in, N, bs, ptr);
        hipMemcpyAsync(cur, ptr, nInt, hipMemcpyDeviceToDevice, stream);
        fill1_k<<<edge_blocks, 256, 0, stream>>>(ei, E, 0, cur, adj);
        agg_k<<<node32_blocks, 256, 0, stream>>>(x, ptr, adj, sum, N);
        gemm_k<<<gemm_blocks, 256, 0, stream>>>(x, W_self, sum, W_s2d, nullptr, nullptr,
                                                b_self, b_s2d, b_d2s, out, N, 0);
        // dir 1: out-aggregation
        scan1_k<<<nb, 256, 0, stream>>>(deg_out, N, bs);
        scan2_k<<<1, 1024, 0, stream>>>(bs, nb);
        scan3_k<<<nb, 256, 0, stream>>>(deg_out, N, bs, ptr);
        hipMemcpyAsync(cur, ptr, nInt, hipMemcpyDeviceToDevice, stream);
        fill1_k<<<edge_blocks, 256, 0, stream>>>(ei, E, 1, cur, adj);
        agg_k<<<node32_blocks, 256, 0, stream>>>(x, ptr, adj, sum, N);
        gemm_k<<<gemm_blocks, 256, 0, stream>>>(sum, W_d2s, nullptr, nullptr, nullptr, nullptr,
                                                nullptr, nullptr, nullptr, out, N, 1);
    } else {
        // plan0: atomic scatter fallback (round-1 structure)
        float* sum = (float*)ws;
        int* deg_in  = (int*)(ws + fbytes);
        int* deg_out = (int*)(ws + fbytes + nInt);

        hipMemsetAsync(ws, 0, fbytes + 2 * nInt, stream);
        deg_k<<<edge_blocks, 256, 0, stream>>>(ei, E, deg_in, deg_out);

        scatter_k<<<node32_blocks == 0 ? 1 : (int)(((size_t)E * 32 + 255) / 256), 256, 0, stream>>>(x, ei, E, sum, 0);
        norm_k<<<node32_blocks, 256, 0, stream>>>(sum, deg_in, N);
        gemm_k<<<gemm_blocks, 256, 0, stream>>>(x, W_self, sum, W_s2d, nullptr, nullptr,
                                                b_self, b_s2d, b_d2s, out, N, 0);
        hipMemsetAsync(sum, 0, fbytes, stream);
        scatter_k<<<(int)(((size_t)E * 32 + 255) / 256), 256, 0, stream>>>(x, ei, E, sum, 1);
        norm_k<<<node32_blocks, 256, 0, stream>>>(sum, deg_out, N);
        gemm_k<<<gemm_blocks, 256, 0, stream>>>(sum, W_d2s, nullptr, nullptr, nullptr, nullptr,
                                                nullptr, nullptr, nullptr, out, N, 1);
    }
}

// Round 4
// 438.711 us; speedup vs baseline: 7.2969x; 1.5732x over previous
//
#include <hip/hip_runtime.h>

// ---------------------------------------------------------------------------
// DirSageConv, bf16-MFMA version.
//   Ab[N][384] bf16 = [ x | 0.5*mean_in(x) | 0.5*mean_out(x) ]
//   out[N][128] f32 = Ab @ Wt_cat^T + (b_self + 0.5*(b_s2d + b_d2s))
// Pipeline: prep_w (transpose+cat weights, fold bias) ; conv_x ; CSR build
// (deg -> scan -> fill) ; agg (gather-mean, both dirs) ; mfma gemm.
// N=100000, E=800000, D=128.
// ---------------------------------------------------------------------------

#define D 128
#define KTOT 384

typedef unsigned short u16;
typedef short bf16x8 __attribute__((ext_vector_type(8)));
typedef float f32x4 __attribute__((ext_vector_type(4)));

__device__ __forceinline__ u16 f2bf(float f) {
    unsigned u = __float_as_uint(f);
    unsigned r = (u + 0x7FFF + ((u >> 16) & 1)) >> 16;   // RNE
    return (u16)r;
}
__device__ __forceinline__ float bf2f(u16 h) {
    return __uint_as_float(((unsigned)h) << 16);
}

// ---------------- weight prep: Wt[n][kt] = W_seg[k][n] (bf16), bias fold ----
__global__ __launch_bounds__(256) void prep_w_k(const float* __restrict__ W0,
                                                const float* __restrict__ W1,
                                                const float* __restrict__ W2,
                                                const float* __restrict__ b0,
                                                const float* __restrict__ b1,
                                                const float* __restrict__ b2,
                                                u16* __restrict__ Wt,
                                                float* __restrict__ biasc) {
    int idx = blockIdx.x * 256 + threadIdx.x;   // 128*384 = 49152
    if (idx < 128 * KTOT) {
        int n = idx / KTOT;          // 0..127
        int kt = idx - n * KTOT;     // 0..383
        int seg = kt >> 7;
        int k = kt & 127;
        const float* W = (seg == 0) ? W0 : (seg == 1) ? W1 : W2;
        Wt[n * KTOT + kt] = f2bf(W[k * D + n]);
    }
    if (idx < D) {
        biasc[idx] = b0[idx] + 0.5f * (b1[idx] + b2[idx]);
    }
}

// ---------------- x -> bf16 into Ab segment 0 ----------------
__global__ __launch_bounds__(256) void conv_x_k(const float* __restrict__ x,
                                                u16* __restrict__ Ab, int N) {
    int gid = blockIdx.x * 256 + threadIdx.x;
    int node = gid >> 5;
    int c = gid & 31;
    if (node >= N) return;
    float4 v = *(const float4*)&x[(size_t)node * D + c * 4];
    ushort4 o;
    o.x = f2bf(v.x); o.y = f2bf(v.y); o.z = f2bf(v.z); o.w = f2bf(v.w);
    *(ushort4*)&Ab[(size_t)node * KTOT + c * 4] = o;
}

// ---------------- degree / CSR build ----------------
__global__ __launch_bounds__(256) void deg_k(const int* __restrict__ ei, int E,
                                             int* __restrict__ deg_in,
                                             int* __restrict__ deg_out) {
    int e = blockIdx.x * 256 + threadIdx.x;
    if (e >= E) return;
    atomicAdd(&deg_out[ei[e]], 1);
    atomicAdd(&deg_in[ei[E + e]], 1);
}

__device__ __forceinline__ int block_incl_scan(int v, int* wsum) {
    int lane = threadIdx.x & 63;
    int wv = threadIdx.x >> 6;
#pragma unroll
    for (int off = 1; off < 64; off <<= 1) {
        int t = __shfl_up(v, off, 64);
        if (lane >= off) v += t;
    }
    if (lane == 63) wsum[wv] = v;
    __syncthreads();
    int add = 0;
    for (int w = 0; w < wv; ++w) add += wsum[w];
    return v + add;
}

__global__ __launch_bounds__(256) void scan1_k(const int* __restrict__ in, int n,
                                               int* __restrict__ bsum) {
    __shared__ int wsum[4];
    int i = blockIdx.x * 256 + threadIdx.x;
    int v = (i < n) ? in[i] : 0;
    int s = block_incl_scan(v, wsum);
    if (threadIdx.x == 255) bsum[blockIdx.x] = s;
}

__global__ __launch_bounds__(1024) void scan2_k(int* __restrict__ bsum, int nb) {
    __shared__ int wsum[16];
    int i = threadIdx.x;
    int v = (i < nb) ? bsum[i] : 0;
    int s = block_incl_scan(v, wsum);
    if (i < nb) bsum[i] = s - v;
}

__global__ __launch_bounds__(256) void scan3_k(const int* __restrict__ in, int n,
                                               const int* __restrict__ bsum,
                                               int* __restrict__ ptr) {
    __shared__ int wsum[4];
    int i = blockIdx.x * 256 + threadIdx.x;
    int v = (i < n) ? in[i] : 0;
    int s = block_incl_scan(v, wsum);
    int off = bsum[blockIdx.x];
    if (i < n) ptr[i] = off + s - v;
    if (i == n - 1) ptr[n] = off + s;
}

__global__ __launch_bounds__(256) void fill2_k(const int* __restrict__ ei, int E,
                                               int* __restrict__ cur_in,
                                               int* __restrict__ cur_out,
                                               int* __restrict__ adj_in,
                                               int* __restrict__ adj_out) {
    int e = blockIdx.x * 256 + threadIdx.x;
    if (e >= E) return;
    int s = ei[e], d = ei[E + e];
    adj_in[atomicAdd(&cur_in[d], 1)] = s;
    adj_out[atomicAdd(&cur_out[s], 1)] = d;
}

// ---------------- gather-mean (bf16 in/out), both directions ----------------
// blockIdx.y = dir. Writes 0.5*mean into Ab[node][128 + dir*128 + ...].
__global__ __launch_bounds__(256) void agg_k(const u16* __restrict__ AbR,
                                             u16* __restrict__ AbW,
                                             const int* __restrict__ ptr_in,
                                             const int* __restrict__ adj_in,
                                             const int* __restrict__ ptr_out,
                                             const int* __restrict__ adj_out,
                                             int N) {
    int gid = blockIdx.x * 256 + threadIdx.x;
    int node = gid >> 5;
    int c = gid & 31;
    if (node >= N) return;
    int dir = blockIdx.y;
    const int* ptr = dir ? ptr_out : ptr_in;
    const int* adj = dir ? adj_out : adj_in;

    int beg = ptr[node], end = ptr[node + 1];
    float4 acc = make_float4(0.f, 0.f, 0.f, 0.f);
    for (int j0 = beg; j0 < end; j0 += 32) {
        int a = (j0 + c < end) ? adj[j0 + c] : 0;
        int m = min(32, end - j0);
        for (int t = 0; t < m; ++t) {
            int nbr = __shfl(a, t, 32);
            ushort4 v = *(const ushort4*)&AbR[(size_t)nbr * KTOT + c * 4];
            acc.x += bf2f(v.x); acc.y += bf2f(v.y);
            acc.z += bf2f(v.z); acc.w += bf2f(v.w);
        }
    }
    float s = 0.5f / fmaxf((float)(end - beg), 1.0f);
    ushort4 o;
    o.x = f2bf(acc.x * s); o.y = f2bf(acc.y * s);
    o.z = f2bf(acc.z * s); o.w = f2bf(acc.w * s);
    *(ushort4*)&AbW[(size_t)node * KTOT + 128 + dir * 128 + c * 4] = o;
}

// ---------------- MFMA GEMM: out[N][128] = Ab[N][384] @ Wt[128][384]^T ------
// 64-row tile / block, 4 waves, wave w -> rows [w*16, w*16+16), 8 n-tiles.
// BK=64 per stage. LDS rows padded 64->72 u16 (144 B) -> only 2-way bank
// aliasing on ds_read_b128 (free per m136).
#define BK 64
__global__ __launch_bounds__(256) void gemm_k(const u16* __restrict__ Ab,
                                              const u16* __restrict__ Wt,
                                              const float* __restrict__ biasc,
                                              float* __restrict__ out, int N) {
    __shared__ u16 As[64 * 72];    // 64 rows x 64 k (+8 pad)
    __shared__ u16 Bs[128 * 72];   // 128 n-rows x 64 k (+8 pad)

    const int tid = threadIdx.x;
    const int row0 = blockIdx.x * 64;
    const int w = tid >> 6;        // wave 0..3
    const int lane = tid & 63;
    const int m = lane & 15;
    const int quad = lane >> 4;

    f32x4 acc[8];
#pragma unroll
    for (int t = 0; t < 8; ++t) acc[t] = (f32x4){0.f, 0.f, 0.f, 0.f};

    for (int kb = 0; kb < KTOT / BK; ++kb) {
        const int k0 = kb * BK;
        __syncthreads();
        // stage A: 64 rows x 64 k = 512 x uint4 (8 u16 each)
#pragma unroll
        for (int i = 0; i < 2; ++i) {
            int f = tid + i * 256;
            int r = f >> 3;        // 0..63
            int q8 = f & 7;        // 0..7
            int grow = row0 + r;
            uint4 v = make_uint4(0u, 0u, 0u, 0u);
            if (grow < N)
                v = *(const uint4*)&Ab[(size_t)grow * KTOT + k0 + q8 * 8];
            *(uint4*)&As[r * 72 + q8 * 8] = v;
        }
        // stage B: 128 n-rows x 64 k = 1024 x uint4
#pragma unroll
        for (int i = 0; i < 4; ++i) {
            int f = tid + i * 256;
            int n = f >> 3;        // 0..127
            int q8 = f & 7;        // 0..7
            uint4 v = *(const uint4*)&Wt[(size_t)n * KTOT + k0 + q8 * 8];
            *(uint4*)&Bs[n * 72 + q8 * 8] = v;
        }
        __syncthreads();

        // A fragment: A[m][k], k = s*32 + quad*8 + j
        bf16x8 a[2];
#pragma unroll
        for (int s = 0; s < 2; ++s)
            a[s] = *(const bf16x8*)&As[(w * 16 + m) * 72 + s * 32 + quad * 8];
#pragma unroll
        for (int t = 0; t < 8; ++t) {
#pragma unroll
            for (int s = 0; s < 2; ++s) {
                bf16x8 b = *(const bf16x8*)&Bs[(t * 16 + m) * 72 + s * 32 + quad * 8];
                acc[t] = __builtin_amdgcn_mfma_f32_16x16x32_bf16(a[s], b, acc[t], 0, 0, 0);
            }
        }
    }

    // epilogue: C/D layout col = lane&15 (N dim), row = quad*4 + reg (M dim)
    const int rowbase = row0 + w * 16 + quad * 4;
#pragma unroll
    for (int t = 0; t < 8; ++t) {
        int col = t * 16 + m;
        float b = biasc[col];
#pragma unroll
        for (int r = 0; r < 4; ++r) {
            int row = rowbase + r;
            if (row < N) out[(size_t)row * D + col] = acc[t][r] + b;
        }
    }
}

// ---------------------------------------------------------------------------

extern "C" void kernel_launch(void* const* d_in, const int* in_sizes, int n_in,
                              void* d_out, int out_size, void* d_ws, size_t ws_size,
                              hipStream_t stream) {
    const float* x      = (const float*)d_in[0];
    const float* W_self = (const float*)d_in[1];
    const float* b_self = (const float*)d_in[2];
    const float* W_s2d  = (const float*)d_in[3];
    const float* b_s2d  = (const float*)d_in[4];
    const float* W_d2s  = (const float*)d_in[5];
    const float* b_d2s  = (const float*)d_in[6];
    const int*   ei     = (const int*)d_in[7];

    const int N = in_sizes[0] / D;
    const int E = in_sizes[7] / 2;
    float* out = (float*)d_out;
    char* ws = (char*)d_ws;

    // ---- workspace layout ----
    size_t o = 0;
    u16* Ab = (u16*)(ws + o);      o += (size_t)N * KTOT * sizeof(u16);
    u16* Wt = (u16*)(ws + o);      o += (size_t)D * KTOT * sizeof(u16);
    float* biasc = (float*)(ws + o); o += D * sizeof(float);
    int* deg_in  = (int*)(ws + o); o += (size_t)N * sizeof(int);
    int* deg_out = (int*)(ws + o); o += (size_t)N * sizeof(int);
    int* ptr_in  = (int*)(ws + o); o += (size_t)(N + 1) * sizeof(int);
    int* ptr_out = (int*)(ws + o); o += (size_t)(N + 1) * sizeof(int);
    int* cur_in  = (int*)(ws + o); o += (size_t)N * sizeof(int);
    int* cur_out = (int*)(ws + o); o += (size_t)N * sizeof(int);
    int* adj_in  = (int*)(ws + o); o += (size_t)E * sizeof(int);
    int* adj_out = (int*)(ws + o); o += (size_t)E * sizeof(int);
    int* bs      = (int*)(ws + o); o += 1024 * sizeof(int);

    const int nb = (N + 255) / 256;
    const int edge_blocks = (E + 255) / 256;
    const int node32_blocks = (int)(((size_t)N * 32 + 255) / 256);
    const int gemm_blocks = (N + 63) / 64;

    // prep: weights/bias + x conversion + degree counts
    hipMemsetAsync(deg_in, 0, 2 * (size_t)N * sizeof(int), stream);
    prep_w_k<<<(128 * KTOT + 255) / 256, 256, 0, stream>>>(W_self, W_s2d, W_d2s,
                                                           b_self, b_s2d, b_d2s,
                                                           Wt, biasc);
    conv_x_k<<<node32_blocks, 256, 0, stream>>>(x, Ab, N);
    deg_k<<<edge_blocks, 256, 0, stream>>>(ei, E, deg_in, deg_out);

    // CSR both directions
    scan1_k<<<nb, 256, 0, stream>>>(deg_in, N, bs);
    scan2_k<<<1, 1024, 0, stream>>>(bs, nb);
    scan3_k<<<nb, 256, 0, stream>>>(deg_in, N, bs, ptr_in);
    scan1_k<<<nb, 256, 0, stream>>>(deg_out, N, bs);
    scan2_k<<<1, 1024, 0, stream>>>(bs, nb);
    scan3_k<<<nb, 256, 0, stream>>>(deg_out, N, bs, ptr_out);
    hipMemcpyAsync(cur_in, ptr_in, (size_t)N * sizeof(int), hipMemcpyDeviceToDevice, stream);
    hipMemcpyAsync(cur_out, ptr_out, (size_t)N * sizeof(int), hipMemcpyDeviceToDevice, stream);
    fill2_k<<<edge_blocks, 256, 0, stream>>>(ei, E, cur_in, cur_out, adj_in, adj_out);

    // aggregation (both dirs)
    dim3 agrid(node32_blocks, 2);
    agg_k<<<agrid, 256, 0, stream>>>(Ab, Ab, ptr_in, adj_in, ptr_out, adj_out, N);

    // fused MFMA GEMM
    gemm_k<<<gemm_blocks, 256, 0, stream>>>(Ab, Wt, biasc, out, N);
}

// Round 5
// 383.946 us; speedup vs baseline: 8.3377x; 1.1426x over previous
//
#include <hip/hip_runtime.h>

// ---------------------------------------------------------------------------
// DirSageConv, bf16-MFMA version.
//   Ab[N][384] bf16 = [ x | 0.5*mean_in(x) | 0.5*mean_out(x) ]
//   out[N][128] f32 = Ab @ Wt_cat^T + (b_self + 0.5*(b_s2d + b_d2s))
// Pipeline: prep_w ; conv_x ; CSR build (deg -> scan -> fill, XCD-partitioned
// to kill scatter write-amplification) ; agg (gather-mean) ; mfma gemm.
// N=100000, E=800000, D=128.
//
// R5: deg/fill partitioned by node range, 8 partitions pinned to XCDs via
// blockIdx%8 round-robin. All adj-line writes for a node come from one XCD
// within a short window -> L2 merges -> WRITE_SIZE ~payload (was 16x).
// ---------------------------------------------------------------------------

#define D 128
#define KTOT 384
#define NPART 8

typedef unsigned short u16;
typedef short bf16x8 __attribute__((ext_vector_type(8)));
typedef float f32x4 __attribute__((ext_vector_type(4)));

__device__ __forceinline__ u16 f2bf(float f) {
    unsigned u = __float_as_uint(f);
    unsigned r = (u + 0x7FFF + ((u >> 16) & 1)) >> 16;   // RNE
    return (u16)r;
}
__device__ __forceinline__ float bf2f(u16 h) {
    return __uint_as_float(((unsigned)h) << 16);
}

// ---------------- weight prep: Wt[n][kt] = W_seg[k][n] (bf16), bias fold ----
__global__ __launch_bounds__(256) void prep_w_k(const float* __restrict__ W0,
                                                const float* __restrict__ W1,
                                                const float* __restrict__ W2,
                                                const float* __restrict__ b0,
                                                const float* __restrict__ b1,
                                                const float* __restrict__ b2,
                                                u16* __restrict__ Wt,
                                                float* __restrict__ biasc) {
    int idx = blockIdx.x * 256 + threadIdx.x;   // 128*384 = 49152
    if (idx < 128 * KTOT) {
        int n = idx / KTOT;          // 0..127
        int kt = idx - n * KTOT;     // 0..383
        int seg = kt >> 7;
        int k = kt & 127;
        const float* W = (seg == 0) ? W0 : (seg == 1) ? W1 : W2;
        Wt[n * KTOT + kt] = f2bf(W[k * D + n]);
    }
    if (idx < D) {
        biasc[idx] = b0[idx] + 0.5f * (b1[idx] + b2[idx]);
    }
}

// ---------------- x -> bf16 into Ab segment 0 ----------------
__global__ __launch_bounds__(256) void conv_x_k(const float* __restrict__ x,
                                                u16* __restrict__ Ab, int N) {
    int gid = blockIdx.x * 256 + threadIdx.x;
    int node = gid >> 5;
    int c = gid & 31;
    if (node >= N) return;
    float4 v = *(const float4*)&x[(size_t)node * D + c * 4];
    ushort4 o;
    o.x = f2bf(v.x); o.y = f2bf(v.y); o.z = f2bf(v.z); o.w = f2bf(v.w);
    *(ushort4*)&Ab[(size_t)node * KTOT + c * 4] = o;
}

// ---------------- degree, XCD-partitioned ----------------
// blockIdx%8 = node partition (maps to XCD via round-robin dispatch),
// blockIdx/8 = edge chunk. Each partition scans all edges, touches only its
// node range -> deg lines stay XCD-local.
__global__ __launch_bounds__(256) void deg_part_k(const int* __restrict__ ei, int E,
                                                  int pdiv, int N,
                                                  int* __restrict__ deg_in,
                                                  int* __restrict__ deg_out) {
    const int part = blockIdx.x & (NPART - 1);
    const int chunk = blockIdx.x >> 3;
    const int nchunk = gridDim.x >> 3;
    const int lo = part * pdiv;
    const int hi = min(N, lo + pdiv);
    const long long per = ((long long)E + nchunk - 1) / nchunk;
    const int beg = (int)((long long)chunk * per);
    const int end = (int)min((long long)E, (long long)(chunk + 1) * per);
    for (int e = beg + threadIdx.x; e < end; e += 256) {
        int s = ei[e], d = ei[E + e];
        if (d >= lo && d < hi) atomicAdd(&deg_in[d], 1);
        if (s >= lo && s < hi) atomicAdd(&deg_out[s], 1);
    }
}

// ---------------- block scan for CSR ptr ----------------
__device__ __forceinline__ int block_incl_scan(int v, int* wsum) {
    int lane = threadIdx.x & 63;
    int wv = threadIdx.x >> 6;
#pragma unroll
    for (int off = 1; off < 64; off <<= 1) {
        int t = __shfl_up(v, off, 64);
        if (lane >= off) v += t;
    }
    if (lane == 63) wsum[wv] = v;
    __syncthreads();
    int add = 0;
    for (int w = 0; w < wv; ++w) add += wsum[w];
    return v + add;
}

__global__ __launch_bounds__(256) void scan1_k(const int* __restrict__ in, int n,
                                               int* __restrict__ bsum) {
    __shared__ int wsum[4];
    int i = blockIdx.x * 256 + threadIdx.x;
    int v = (i < n) ? in[i] : 0;
    int s = block_incl_scan(v, wsum);
    if (threadIdx.x == 255) bsum[blockIdx.x] = s;
}

__global__ __launch_bounds__(1024) void scan2_k(int* __restrict__ bsum, int nb) {
    __shared__ int wsum[16];
    int i = threadIdx.x;
    int v = (i < nb) ? bsum[i] : 0;
    int s = block_incl_scan(v, wsum);
    if (i < nb) bsum[i] = s - v;
}

__global__ __launch_bounds__(256) void scan3_k(const int* __restrict__ in, int n,
                                               const int* __restrict__ bsum,
                                               int* __restrict__ ptr) {
    __shared__ int wsum[4];
    int i = blockIdx.x * 256 + threadIdx.x;
    int v = (i < n) ? in[i] : 0;
    int s = block_incl_scan(v, wsum);
    int off = bsum[blockIdx.x];
    if (i < n) ptr[i] = off + s - v;
    if (i == n - 1) ptr[n] = off + s;
}

// ---------------- CSR fill, XCD-partitioned ----------------
__global__ __launch_bounds__(256) void fill_part_k(const int* __restrict__ ei, int E,
                                                   int pdiv, int N,
                                                   int* __restrict__ cur_in,
                                                   int* __restrict__ cur_out,
                                                   int* __restrict__ adj_in,
                                                   int* __restrict__ adj_out) {
    const int part = blockIdx.x & (NPART - 1);
    const int chunk = blockIdx.x >> 3;
    const int nchunk = gridDim.x >> 3;
    const int lo = part * pdiv;
    const int hi = min(N, lo + pdiv);
    const long long per = ((long long)E + nchunk - 1) / nchunk;
    const int beg = (int)((long long)chunk * per);
    const int end = (int)min((long long)E, (long long)(chunk + 1) * per);
    for (int e = beg + threadIdx.x; e < end; e += 256) {
        int s = ei[e], d = ei[E + e];
        if (d >= lo && d < hi) adj_in[atomicAdd(&cur_in[d], 1)] = s;
        if (s >= lo && s < hi) adj_out[atomicAdd(&cur_out[s], 1)] = d;
    }
}

// ---------------- gather-mean (bf16 in/out), both directions ----------------
// blockIdx.y = dir. Writes 0.5*mean into Ab[node][128 + dir*128 + ...].
__global__ __launch_bounds__(256) void agg_k(const u16* __restrict__ AbR,
                                             u16* __restrict__ AbW,
                                             const int* __restrict__ ptr_in,
                                             const int* __restrict__ adj_in,
                                             const int* __restrict__ ptr_out,
                                             const int* __restrict__ adj_out,
                                             int N) {
    int gid = blockIdx.x * 256 + threadIdx.x;
    int node = gid >> 5;
    int c = gid & 31;
    if (node >= N) return;
    int dir = blockIdx.y;
    const int* ptr = dir ? ptr_out : ptr_in;
    const int* adj = dir ? adj_out : adj_in;

    int beg = ptr[node], end = ptr[node + 1];
    float4 acc = make_float4(0.f, 0.f, 0.f, 0.f);
    for (int j0 = beg; j0 < end; j0 += 32) {
        int a = (j0 + c < end) ? adj[j0 + c] : 0;
        int m = min(32, end - j0);
        for (int t = 0; t < m; ++t) {
            int nbr = __shfl(a, t, 32);
            ushort4 v = *(const ushort4*)&AbR[(size_t)nbr * KTOT + c * 4];
            acc.x += bf2f(v.x); acc.y += bf2f(v.y);
            acc.z += bf2f(v.z); acc.w += bf2f(v.w);
        }
    }
    float s = 0.5f / fmaxf((float)(end - beg), 1.0f);
    ushort4 o;
    o.x = f2bf(acc.x * s); o.y = f2bf(acc.y * s);
    o.z = f2bf(acc.z * s); o.w = f2bf(acc.w * s);
    *(ushort4*)&AbW[(size_t)node * KTOT + 128 + dir * 128 + c * 4] = o;
}

// ---------------- MFMA GEMM: out[N][128] = Ab[N][384] @ Wt[128][384]^T ------
#define BK 64
__global__ __launch_bounds__(256) void gemm_k(const u16* __restrict__ Ab,
                                              const u16* __restrict__ Wt,
                                              const float* __restrict__ biasc,
                                              float* __restrict__ out, int N) {
    __shared__ u16 As[64 * 72];    // 64 rows x 64 k (+8 pad)
    __shared__ u16 Bs[128 * 72];   // 128 n-rows x 64 k (+8 pad)

    const int tid = threadIdx.x;
    const int row0 = blockIdx.x * 64;
    const int w = tid >> 6;        // wave 0..3
    const int lane = tid & 63;
    const int m = lane & 15;
    const int quad = lane >> 4;

    f32x4 acc[8];
#pragma unroll
    for (int t = 0; t < 8; ++t) acc[t] = (f32x4){0.f, 0.f, 0.f, 0.f};

    for (int kb = 0; kb < KTOT / BK; ++kb) {
        const int k0 = kb * BK;
        __syncthreads();
#pragma unroll
        for (int i = 0; i < 2; ++i) {
            int f = tid + i * 256;
            int r = f >> 3;
            int q8 = f & 7;
            int grow = row0 + r;
            uint4 v = make_uint4(0u, 0u, 0u, 0u);
            if (grow < N)
                v = *(const uint4*)&Ab[(size_t)grow * KTOT + k0 + q8 * 8];
            *(uint4*)&As[r * 72 + q8 * 8] = v;
        }
#pragma unroll
        for (int i = 0; i < 4; ++i) {
            int f = tid + i * 256;
            int n = f >> 3;
            int q8 = f & 7;
            uint4 v = *(const uint4*)&Wt[(size_t)n * KTOT + k0 + q8 * 8];
            *(uint4*)&Bs[n * 72 + q8 * 8] = v;
        }
        __syncthreads();

        bf16x8 a[2];
#pragma unroll
        for (int s = 0; s < 2; ++s)
            a[s] = *(const bf16x8*)&As[(w * 16 + m) * 72 + s * 32 + quad * 8];
#pragma unroll
        for (int t = 0; t < 8; ++t) {
#pragma unroll
            for (int s = 0; s < 2; ++s) {
                bf16x8 b = *(const bf16x8*)&Bs[(t * 16 + m) * 72 + s * 32 + quad * 8];
                acc[t] = __builtin_amdgcn_mfma_f32_16x16x32_bf16(a[s], b, acc[t], 0, 0, 0);
            }
        }
    }

    const int rowbase = row0 + w * 16 + quad * 4;
#pragma unroll
    for (int t = 0; t < 8; ++t) {
        int col = t * 16 + m;
        float b = biasc[col];
#pragma unroll
        for (int r = 0; r < 4; ++r) {
            int row = rowbase + r;
            if (row < N) out[(size_t)row * D + col] = acc[t][r] + b;
        }
    }
}

// ---------------------------------------------------------------------------

extern "C" void kernel_launch(void* const* d_in, const int* in_sizes, int n_in,
                              void* d_out, int out_size, void* d_ws, size_t ws_size,
                              hipStream_t stream) {
    const float* x      = (const float*)d_in[0];
    const float* W_self = (const float*)d_in[1];
    const float* b_self = (const float*)d_in[2];
    const float* W_s2d  = (const float*)d_in[3];
    const float* b_s2d  = (const float*)d_in[4];
    const float* W_d2s  = (const float*)d_in[5];
    const float* b_d2s  = (const float*)d_in[6];
    const int*   ei     = (const int*)d_in[7];

    const int N = in_sizes[0] / D;
    const int E = in_sizes[7] / 2;
    float* out = (float*)d_out;
    char* ws = (char*)d_ws;

    // ---- workspace layout ----
    size_t o = 0;
    u16* Ab = (u16*)(ws + o);      o += (size_t)N * KTOT * sizeof(u16);
    u16* Wt = (u16*)(ws + o);      o += (size_t)D * KTOT * sizeof(u16);
    float* biasc = (float*)(ws + o); o += D * sizeof(float);
    int* deg_in  = (int*)(ws + o); o += (size_t)N * sizeof(int);
    int* deg_out = (int*)(ws + o); o += (size_t)N * sizeof(int);
    int* ptr_in  = (int*)(ws + o); o += (size_t)(N + 1) * sizeof(int);
    int* ptr_out = (int*)(ws + o); o += (size_t)(N + 1) * sizeof(int);
    int* cur_in  = (int*)(ws + o); o += (size_t)N * sizeof(int);
    int* cur_out = (int*)(ws + o); o += (size_t)N * sizeof(int);
    int* adj_in  = (int*)(ws + o); o += (size_t)E * sizeof(int);
    int* adj_out = (int*)(ws + o); o += (size_t)E * sizeof(int);
    int* bs      = (int*)(ws + o); o += 1024 * sizeof(int);

    const int nb = (N + 255) / 256;
    const int node32_blocks = (int)(((size_t)N * 32 + 255) / 256);
    const int gemm_blocks = (N + 63) / 64;
    const int pdiv = (N + NPART - 1) / NPART;       // 12500
    const int part_grid = NPART * 120;              // 8 partitions x 120 chunks

    // prep: weights/bias + x conversion + degree counts
    hipMemsetAsync(deg_in, 0, 2 * (size_t)N * sizeof(int), stream);
    prep_w_k<<<(128 * KTOT + 255) / 256, 256, 0, stream>>>(W_self, W_s2d, W_d2s,
                                                           b_self, b_s2d, b_d2s,
                                                           Wt, biasc);
    conv_x_k<<<node32_blocks, 256, 0, stream>>>(x, Ab, N);
    deg_part_k<<<part_grid, 256, 0, stream>>>(ei, E, pdiv, N, deg_in, deg_out);

    // CSR both directions
    scan1_k<<<nb, 256, 0, stream>>>(deg_in, N, bs);
    scan2_k<<<1, 1024, 0, stream>>>(bs, nb);
    scan3_k<<<nb, 256, 0, stream>>>(deg_in, N, bs, ptr_in);
    scan1_k<<<nb, 256, 0, stream>>>(deg_out, N, bs);
    scan2_k<<<1, 1024, 0, stream>>>(bs, nb);
    scan3_k<<<nb, 256, 0, stream>>>(deg_out, N, bs, ptr_out);
    hipMemcpyAsync(cur_in, ptr_in, (size_t)N * sizeof(int), hipMemcpyDeviceToDevice, stream);
    hipMemcpyAsync(cur_out, ptr_out, (size_t)N * sizeof(int), hipMemcpyDeviceToDevice, stream);
    fill_part_k<<<part_grid, 256, 0, stream>>>(ei, E, pdiv, N, cur_in, cur_out,
                                               adj_in, adj_out);

    // aggregation (both dirs)
    dim3 agrid(node32_blocks, 2);
    agg_k<<<agrid, 256, 0, stream>>>(Ab, Ab, ptr_in, adj_in, ptr_out, adj_out, N);

    // fused MFMA GEMM
    gemm_k<<<gemm_blocks, 256, 0, stream>>>(Ab, Wt, biasc, out, N);
}

// Round 6
// 350.612 us; speedup vs baseline: 9.1304x; 1.0951x over previous
//
#include <hip/hip_runtime.h>

// ---------------------------------------------------------------------------
// DirSageConv, bf16-MFMA + fp8-gather version.
//   Ab[N][384] bf16 = [ x | 0.5*mean_in(x) | 0.5*mean_out(x) ]
//   xq[N][128] fp8  = e4m3(x)                (gather payload, half bytes)
//   out[N][128] f32 = Ab @ Wt_cat^T + (b_self + 0.5*(b_s2d + b_d2s))
// Combined CSR over 2N node-dir space (idx = dir*N + node), one scan chain.
// fill is XCD-partitioned (R5: kills 17x adj write amplification).
// N=100000, E=800000, D=128.
// ---------------------------------------------------------------------------

#define D 128
#define KTOT 384
#define NPART 8

typedef unsigned short u16;
typedef short bf16x8 __attribute__((ext_vector_type(8)));
typedef float f32x4 __attribute__((ext_vector_type(4)));
typedef float f32x2 __attribute__((ext_vector_type(2)));

__device__ __forceinline__ u16 f2bf(float f) {
    unsigned u = __float_as_uint(f);
    unsigned r = (u + 0x7FFF + ((u >> 16) & 1)) >> 16;   // RNE
    return (u16)r;
}

// ---------------- weight prep: Wt[n][kt] = W_seg[k][n] (bf16), bias fold ----
__global__ __launch_bounds__(256) void prep_w_k(const float* __restrict__ W0,
                                                const float* __restrict__ W1,
                                                const float* __restrict__ W2,
                                                const float* __restrict__ b0,
                                                const float* __restrict__ b1,
                                                const float* __restrict__ b2,
                                                u16* __restrict__ Wt,
                                                float* __restrict__ biasc) {
    int idx = blockIdx.x * 256 + threadIdx.x;   // 128*384 = 49152
    if (idx < 128 * KTOT) {
        int n = idx / KTOT;          // 0..127
        int kt = idx - n * KTOT;     // 0..383
        int seg = kt >> 7;
        int k = kt & 127;
        const float* W = (seg == 0) ? W0 : (seg == 1) ? W1 : W2;
        Wt[n * KTOT + kt] = f2bf(W[k * D + n]);
    }
    if (idx < D) {
        biasc[idx] = b0[idx] + 0.5f * (b1[idx] + b2[idx]);
    }
}

// ---------------- x -> bf16 seg0 of Ab, and fp8 copy xq ----------------
__global__ __launch_bounds__(256) void conv_x_k(const float* __restrict__ x,
                                                u16* __restrict__ Ab,
                                                unsigned* __restrict__ xq,  // N*32 words
                                                int N) {
    int gid = blockIdx.x * 256 + threadIdx.x;
    int node = gid >> 5;
    int c = gid & 31;
    if (node >= N) return;
    float4 v = *(const float4*)&x[(size_t)node * D + c * 4];
    ushort4 o;
    o.x = f2bf(v.x); o.y = f2bf(v.y); o.z = f2bf(v.z); o.w = f2bf(v.w);
    *(ushort4*)&Ab[(size_t)node * KTOT + c * 4] = o;
    // pack 4 fp8 (e4m3, RNE) into one dword
    int q = __builtin_amdgcn_cvt_pk_fp8_f32(v.x, v.y, 0, false);
    q = __builtin_amdgcn_cvt_pk_fp8_f32(v.z, v.w, q, true);
    xq[(size_t)node * 32 + c] = (unsigned)q;
}

// ---------------- degrees over combined 2N space ----------------
// deg[d] (in-degree), deg[N+s] (out-degree)
__global__ __launch_bounds__(256) void deg_k(const int* __restrict__ ei, int E, int N,
                                             int* __restrict__ deg) {
    int e = blockIdx.x * 256 + threadIdx.x;
    if (e >= E) return;
    int s = ei[e], d = ei[E + e];
    atomicAdd(&deg[d], 1);
    atomicAdd(&deg[N + s], 1);
}

// ---------------- block scan for CSR ptr ----------------
__device__ __forceinline__ int block_incl_scan(int v, int* wsum) {
    int lane = threadIdx.x & 63;
    int wv = threadIdx.x >> 6;
#pragma unroll
    for (int off = 1; off < 64; off <<= 1) {
        int t = __shfl_up(v, off, 64);
        if (lane >= off) v += t;
    }
    if (lane == 63) wsum[wv] = v;
    __syncthreads();
    int add = 0;
    for (int w = 0; w < wv; ++w) add += wsum[w];
    return v + add;
}

__global__ __launch_bounds__(256) void scan1_k(const int* __restrict__ in, int n,
                                               int* __restrict__ bsum) {
    __shared__ int wsum[4];
    int i = blockIdx.x * 256 + threadIdx.x;
    int v = (i < n) ? in[i] : 0;
    int s = block_incl_scan(v, wsum);
    if (threadIdx.x == 255) bsum[blockIdx.x] = s;
}

__global__ __launch_bounds__(1024) void scan2_k(int* __restrict__ bsum, int nb) {
    __shared__ int wsum[16];
    int i = threadIdx.x;
    int v = (i < nb) ? bsum[i] : 0;
    int s = block_incl_scan(v, wsum);
    if (i < nb) bsum[i] = s - v;
}

__global__ __launch_bounds__(256) void scan3_k(const int* __restrict__ in, int n,
                                               const int* __restrict__ bsum,
                                               int* __restrict__ ptr) {
    __shared__ int wsum[4];
    int i = blockIdx.x * 256 + threadIdx.x;
    int v = (i < n) ? in[i] : 0;
    int s = block_incl_scan(v, wsum);
    int off = bsum[blockIdx.x];
    if (i < n) ptr[i] = off + s - v;
    if (i == n - 1) ptr[n] = off + s;
}

// ---------------- CSR fill over combined space, XCD-partitioned -------------
// blockIdx%8 = partition of [0,2N), blockIdx/8 = edge chunk. A partition only
// writes adj entries for its node range -> adj lines stay XCD-local.
__global__ __launch_bounds__(256) void fill_part_k(const int* __restrict__ ei, int E,
                                                   int pdiv, int N,
                                                   int* __restrict__ cur,
                                                   int* __restrict__ adj) {
    const int part = blockIdx.x & (NPART - 1);
    const int chunk = blockIdx.x >> 3;
    const int nchunk = gridDim.x >> 3;
    const int lo = part * pdiv;
    const int hi = min(2 * N, lo + pdiv);
    const long long per = ((long long)E + nchunk - 1) / nchunk;
    const int beg = (int)((long long)chunk * per);
    const int end = (int)min((long long)E, (long long)(chunk + 1) * per);
    for (int e = beg + threadIdx.x; e < end; e += 256) {
        int s = ei[e], d = ei[E + e];
        if (d >= lo && d < hi) adj[atomicAdd(&cur[d], 1)] = s;          // in
        int os = N + s;
        if (os >= lo && os < hi) adj[atomicAdd(&cur[os], 1)] = d;       // out
    }
}

// ---------------- gather-mean: fp8 gather, bf16 output ----------------
// 32 threads per (node,dir). lane = tid&31; h = lane>>4 picks one of two
// neighbors per iteration; c8 = lane&15 -> 8 features (8 fp8 = uint2 load).
// Writes 0.5*mean as bf16 into Ab[node][128 + dir*128 ...].
__global__ __launch_bounds__(256) void agg_k(const unsigned* __restrict__ xq,
                                             u16* __restrict__ Ab,
                                             const int* __restrict__ ptr,
                                             const int* __restrict__ adj,
                                             int N) {
    int gid = blockIdx.x * 256 + threadIdx.x;
    int node = gid >> 5;
    int lane = gid & 31;
    if (node >= N) return;
    const int dir = blockIdx.y;
    const int ci = dir * N + node;           // combined index
    const int h = lane >> 4;                 // 0/1: neighbor parity
    const int c8 = lane & 15;                // feature octet

    int beg = ptr[ci], end = ptr[ci + 1];
    float acc[8];
#pragma unroll
    for (int j = 0; j < 8; ++j) acc[j] = 0.f;

    for (int j0 = beg; j0 < end; j0 += 32) {
        int a = (j0 + lane < end) ? adj[j0 + lane] : 0;
        int m = min(32, end - j0);
        for (int t = 0; t < m; t += 2) {
            int my = t + h;
            int nbr = __shfl(a, (my < m) ? my : 0, 32);
            if (my < m) {
                uint2 q = *(const uint2*)((const char*)xq + ((size_t)nbr * 128 + c8 * 8));
                f32x2 p0 = __builtin_amdgcn_cvt_pk_f32_fp8((int)q.x, false);
                f32x2 p1 = __builtin_amdgcn_cvt_pk_f32_fp8((int)q.x, true);
                f32x2 p2 = __builtin_amdgcn_cvt_pk_f32_fp8((int)q.y, false);
                f32x2 p3 = __builtin_amdgcn_cvt_pk_f32_fp8((int)q.y, true);
                acc[0] += p0.x; acc[1] += p0.y; acc[2] += p1.x; acc[3] += p1.y;
                acc[4] += p2.x; acc[5] += p2.y; acc[6] += p3.x; acc[7] += p3.y;
            }
        }
    }
    // combine the two neighbor-parity halves (lane ^ 16)
#pragma unroll
    for (int j = 0; j < 8; ++j) acc[j] += __shfl_xor(acc[j], 16, 32);

    if (h == 0) {
        float s = 0.5f / fmaxf((float)(end - beg), 1.0f);
        uint4 o;
        o.x = (unsigned)f2bf(acc[0] * s) | ((unsigned)f2bf(acc[1] * s) << 16);
        o.y = (unsigned)f2bf(acc[2] * s) | ((unsigned)f2bf(acc[3] * s) << 16);
        o.z = (unsigned)f2bf(acc[4] * s) | ((unsigned)f2bf(acc[5] * s) << 16);
        o.w = (unsigned)f2bf(acc[6] * s) | ((unsigned)f2bf(acc[7] * s) << 16);
        *(uint4*)&Ab[(size_t)node * KTOT + 128 + dir * 128 + c8 * 8] = o;
    }
}

// ---------------- MFMA GEMM: out[N][128] = Ab[N][384] @ Wt[128][384]^T ------
#define BK 64
__global__ __launch_bounds__(256) void gemm_k(const u16* __restrict__ Ab,
                                              const u16* __restrict__ Wt,
                                              const float* __restrict__ biasc,
                                              float* __restrict__ out, int N) {
    __shared__ u16 As[64 * 72];    // 64 rows x 64 k (+8 pad)
    __shared__ u16 Bs[128 * 72];   // 128 n-rows x 64 k (+8 pad)

    const int tid = threadIdx.x;
    const int row0 = blockIdx.x * 64;
    const int w = tid >> 6;        // wave 0..3
    const int lane = tid & 63;
    const int m = lane & 15;
    const int quad = lane >> 4;

    f32x4 acc[8];
#pragma unroll
    for (int t = 0; t < 8; ++t) acc[t] = (f32x4){0.f, 0.f, 0.f, 0.f};

    for (int kb = 0; kb < KTOT / BK; ++kb) {
        const int k0 = kb * BK;
        __syncthreads();
#pragma unroll
        for (int i = 0; i < 2; ++i) {
            int f = tid + i * 256;
            int r = f >> 3;
            int q8 = f & 7;
            int grow = row0 + r;
            uint4 v = make_uint4(0u, 0u, 0u, 0u);
            if (grow < N)
                v = *(const uint4*)&Ab[(size_t)grow * KTOT + k0 + q8 * 8];
            *(uint4*)&As[r * 72 + q8 * 8] = v;
        }
#pragma unroll
        for (int i = 0; i < 4; ++i) {
            int f = tid + i * 256;
            int n = f >> 3;
            int q8 = f & 7;
            uint4 v = *(const uint4*)&Wt[(size_t)n * KTOT + k0 + q8 * 8];
            *(uint4*)&Bs[n * 72 + q8 * 8] = v;
        }
        __syncthreads();

        bf16x8 a[2];
#pragma unroll
        for (int s = 0; s < 2; ++s)
            a[s] = *(const bf16x8*)&As[(w * 16 + m) * 72 + s * 32 + quad * 8];
#pragma unroll
        for (int t = 0; t < 8; ++t) {
#pragma unroll
            for (int s = 0; s < 2; ++s) {
                bf16x8 b = *(const bf16x8*)&Bs[(t * 16 + m) * 72 + s * 32 + quad * 8];
                acc[t] = __builtin_amdgcn_mfma_f32_16x16x32_bf16(a[s], b, acc[t], 0, 0, 0);
            }
        }
    }

    const int rowbase = row0 + w * 16 + quad * 4;
#pragma unroll
    for (int t = 0; t < 8; ++t) {
        int col = t * 16 + m;
        float b = biasc[col];
#pragma unroll
        for (int r = 0; r < 4; ++r) {
            int row = rowbase + r;
            if (row < N) out[(size_t)row * D + col] = acc[t][r] + b;
        }
    }
}

// ---------------------------------------------------------------------------

extern "C" void kernel_launch(void* const* d_in, const int* in_sizes, int n_in,
                              void* d_out, int out_size, void* d_ws, size_t ws_size,
                              hipStream_t stream) {
    const float* x      = (const float*)d_in[0];
    const float* W_self = (const float*)d_in[1];
    const float* b_self = (const float*)d_in[2];
    const float* W_s2d  = (const float*)d_in[3];
    const float* b_s2d  = (const float*)d_in[4];
    const float* W_d2s  = (const float*)d_in[5];
    const float* b_d2s  = (const float*)d_in[6];
    const int*   ei     = (const int*)d_in[7];

    const int N = in_sizes[0] / D;
    const int E = in_sizes[7] / 2;
    float* out = (float*)d_out;
    char* ws = (char*)d_ws;

    // ---- workspace layout (~99 MB; R2 proved >= ~111 MB available) ----
    size_t o = 0;
    u16* Ab = (u16*)(ws + o);        o += (size_t)N * KTOT * sizeof(u16);
    unsigned* xq = (unsigned*)(ws + o); o += (size_t)N * 32 * sizeof(unsigned);
    u16* Wt = (u16*)(ws + o);        o += (size_t)D * KTOT * sizeof(u16);
    float* biasc = (float*)(ws + o); o += D * sizeof(float);
    int* deg = (int*)(ws + o);       o += (size_t)2 * N * sizeof(int);
    int* ptr = (int*)(ws + o);       o += ((size_t)2 * N + 1) * sizeof(int);
    int* cur = (int*)(ws + o);       o += (size_t)2 * N * sizeof(int);
    int* adj = (int*)(ws + o);       o += (size_t)2 * E * sizeof(int);
    int* bs  = (int*)(ws + o);       o += 1024 * sizeof(int);

    const int n2 = 2 * N;
    const int nb2 = (n2 + 255) / 256;               // 782 <= 1024
    const int edge_blocks = (E + 255) / 256;
    const int node32_blocks = (int)(((size_t)N * 32 + 255) / 256);
    const int gemm_blocks = (N + 63) / 64;
    const int pdiv = (n2 + NPART - 1) / NPART;      // 25000
    const int part_grid = NPART * 120;

    // prep: weights/bias, x conversion (bf16 + fp8), degrees
    hipMemsetAsync(deg, 0, (size_t)n2 * sizeof(int), stream);
    prep_w_k<<<(128 * KTOT + 255) / 256, 256, 0, stream>>>(W_self, W_s2d, W_d2s,
                                                           b_self, b_s2d, b_d2s,
                                                           Wt, biasc);
    conv_x_k<<<node32_blocks, 256, 0, stream>>>(x, Ab, xq, N);
    deg_k<<<edge_blocks, 256, 0, stream>>>(ei, E, N, deg);

    // combined CSR (one scan chain over 2N)
    scan1_k<<<nb2, 256, 0, stream>>>(deg, n2, bs);
    scan2_k<<<1, 1024, 0, stream>>>(bs, nb2);
    scan3_k<<<nb2, 256, 0, stream>>>(deg, n2, bs, ptr);
    hipMemcpyAsync(cur, ptr, (size_t)n2 * sizeof(int), hipMemcpyDeviceToDevice, stream);
    fill_part_k<<<part_grid, 256, 0, stream>>>(ei, E, pdiv, N, cur, adj);

    // aggregation (both dirs), fp8 gather
    dim3 agrid(node32_blocks, 2);
    agg_k<<<agrid, 256, 0, stream>>>(xq, Ab, ptr, adj, N);

    // fused MFMA GEMM
    gemm_k<<<gemm_blocks, 256, 0, stream>>>(Ab, Wt, biasc, out, N);
}